// Round 13
// baseline (543.181 us; speedup 1.0000x reference)
//
#include <hip/hip_runtime.h>

// Problem constants
#define BB 16
#define TT 32
#define NN 1024
#define DD 64
#define HH 64
#define BN 16384          // B*N
#define GH 128
#define RR 128
#define OO 32

typedef __attribute__((ext_vector_type(8))) short short8;
typedef __attribute__((ext_vector_type(4))) float f32x4;
typedef __attribute__((ext_vector_type(8))) _Float16 half8;
typedef __attribute__((ext_vector_type(2))) __fp16 fp16x2;

#define MFMA(A, B, C) __builtin_amdgcn_mfma_f32_16x16x32_bf16((A), (B), (C), 0, 0, 0)
#define MF16(A, B, C) __builtin_amdgcn_mfma_f32_16x16x32_f16((A), (B), (C), 0, 0, 0)

__device__ __forceinline__ unsigned short f2bf(float x) {
  unsigned u = __float_as_uint(x);
  unsigned r = (u + 0x7FFFu + ((u >> 16) & 1u)) >> 16;
  return (unsigned short)r;
}
__device__ __forceinline__ float bf2f(unsigned short h) {
  return __uint_as_float(((unsigned)h) << 16);
}
// v_rcp_f32 (~1 ULP): plain 1/x without fast-math is ~10 VALU + ~40cy chain.
__device__ __forceinline__ float rcp_fast(float x) {
  return __builtin_amdgcn_rcpf(x);
}
__device__ __forceinline__ float sigmoid_fast(float x) {
  return rcp_fast(1.0f + __expf(-x));
}
__device__ __forceinline__ float tanh_fast(float x) {
  return fmaf(-2.0f, rcp_fast(__expf(2.0f * x) + 1.0f), 1.0f);
}
__device__ __forceinline__ float leaky02(float x) {
  return fmaxf(x, 0.2f * x);
}

// ---------------------------------------------------------------------------
// Fused 2-layer GRU, v6 (unchanged from R12).
// ---------------------------------------------------------------------------
__global__ __launch_bounds__(512, 4) void gru_fused_kernel(
    const float* __restrict__ x,
    const float* __restrict__ Wih0, const float* __restrict__ Whh0,
    const float* __restrict__ bih0, const float* __restrict__ bhh0,
    const float* __restrict__ Wih1, const float* __restrict__ Whh1,
    const float* __restrict__ bih1, const float* __restrict__ bhh1,
    float* __restrict__ feat)
{
  __shared__ _Float16 sX[2][1024];     // [buf][seq*64 + swz(k)] : 4 KB
  __shared__ _Float16 sH0[2][1024];    // [buf][...] : 4 KB
  __shared__ _Float16 sH1[2][1024];    // [buf][...] : 4 KB

  const int tid = threadIdx.x;
  const int gbase = blockIdx.x * 16;

  const int w = tid >> 6, l = tid & 63;
  const int layer = w >> 2;            // 0 or 1
  const int jt = w & 3;                // 16-col j-group
  const int c = l & 15;                // A row (seq) / D col (j)
  const int rq = l >> 4;               // A k-chunk / D row-group

  const float* Wih = layer ? Wih1 : Wih0;
  const float* Whh = layer ? Whh1 : Whh0;
  const float* bihp = layer ? bih1 : bih0;
  const float* bhhp = layer ? bhh1 : bhh0;

  // ---- weight fragments: global -> reg, fp16 single-plane. [gate][src][ks]
  half8 wf[3][2][2];
#pragma unroll
  for (int g = 0; g < 3; ++g) {
    const int row = g * 64 + jt * 16 + c;
#pragma unroll
    for (int ks = 0; ks < 2; ++ks) {
      const int col = ks * 32 + (rq << 3);
      float4 i0 = *reinterpret_cast<const float4*>(Wih + row * 64 + col);
      float4 i1 = *reinterpret_cast<const float4*>(Wih + row * 64 + col + 4);
      float4 h0 = *reinterpret_cast<const float4*>(Whh + row * 64 + col);
      float4 h1 = *reinterpret_cast<const float4*>(Whh + row * 64 + col + 4);
      float wi[8] = {i0.x, i0.y, i0.z, i0.w, i1.x, i1.y, i1.z, i1.w};
      float wh[8] = {h0.x, h0.y, h0.z, h0.w, h1.x, h1.y, h1.z, h1.w};
      half8 vih, vhh;
#pragma unroll
      for (int e = 0; e < 8; ++e) {
        vih[e] = (_Float16)wi[e];
        vhh[e] = (_Float16)wh[e];
      }
      wf[g][0][ks] = vih;
      wf[g][1][ks] = vhh;
    }
  }

  // ---- X staging role ----
  const int sseq = tid >> 5;           // 0..15
  const int kp = (tid & 31) << 1;      // even k
  const float* xrow = x + (size_t)(gbase + sseq) * (TT * 64) + kp;
  const int sxoff = sseq * 64 + (kp ^ ((sseq & 7) << 3));

  for (int i = tid; i < 1024; i += 512) {
    sH0[0][i] = (_Float16)0.0f;
    sH1[0][i] = (_Float16)0.0f;
  }

  float2 p = *reinterpret_cast<const float2*>(xrow);
  *reinterpret_cast<fp16x2*>(&sX[0][sxoff]) = __builtin_amdgcn_cvt_pkrtz(p.x, p.y);
  p = *reinterpret_cast<const float2*>(xrow + 64);

  const int jj = jt * 16 + c;
  const float br  = bihp[jj]       + bhhp[jj];
  const float bz  = bihp[64 + jj]  + bhhp[64 + jj];
  const float bni = bihp[128 + jj];
  const float bnh = bhhp[128 + jj];

  int ao[2];
#pragma unroll
  for (int ks = 0; ks < 2; ++ks)
    ao[ks] = c * 64 + (((ks << 5) + (rq << 3)) ^ ((c & 7) << 3));
  int hoff[4];
#pragma unroll
  for (int q = 0; q < 4; ++q) {
    const int seq = (rq << 2) + q;
    hoff[q] = seq * 64 + (jj ^ ((seq & 7) << 3));
  }

  float h[4] = {0.0f, 0.0f, 0.0f, 0.0f};

  for (int t = 0; t <= TT; ++t) {
    __syncthreads();
    const int cb = t & 1, nb = cb ^ 1;
    if (t + 1 < TT)
      *reinterpret_cast<fp16x2*>(&sX[nb][sxoff]) = __builtin_amdgcn_cvt_pkrtz(p.x, p.y);
    if (t + 2 < TT)
      p = *reinterpret_cast<const float2*>(xrow + (t + 2) * 64);

    const bool active = layer ? (t >= 1) : (t < TT);
    if (active) {
      const _Float16* xsrc = layer ? &sH0[cb][0] : &sX[cb][0];
      const _Float16* hsrc = layer ? &sH1[nb][0] : &sH0[cb][0];
      _Float16* hdst       = layer ? &sH1[cb][0] : &sH0[nb][0];

      f32x4 accr  = (f32x4){br, br, br, br};
      f32x4 accz  = (f32x4){bz, bz, bz, bz};
      f32x4 accni = (f32x4){bni, bni, bni, bni};
      f32x4 accnh = (f32x4){bnh, bnh, bnh, bnh};

#pragma unroll
      for (int ks = 0; ks < 2; ++ks) {
        const half8 xa = *reinterpret_cast<const half8*>(xsrc + ao[ks]);
        const half8 ha = *reinterpret_cast<const half8*>(hsrc + ao[ks]);
        accr  = MF16(xa, wf[0][0][ks], accr);
        accr  = MF16(ha, wf[0][1][ks], accr);
        accz  = MF16(xa, wf[1][0][ks], accz);
        accz  = MF16(ha, wf[1][1][ks], accz);
        accni = MF16(xa, wf[2][0][ks], accni);
        accnh = MF16(ha, wf[2][1][ks], accnh);
      }

#pragma unroll
      for (int q = 0; q < 4; ++q) {
        float rg = sigmoid_fast(accr[q]);
        float zg = sigmoid_fast(accz[q]);
        float ng = tanh_fast(fmaf(rg, accnh[q], accni[q]));
        float hv = fmaf(zg, h[q] - ng, ng);   // n + z*(h-n)
        h[q] = hv;
        hdst[hoff[q]] = (_Float16)hv;
      }
    }
  }

  if (layer == 1) {
#pragma unroll
    for (int q = 0; q < 4; ++q) {
      const int seq = (rq << 2) + q;
      feat[(size_t)(gbase + seq) * 64 + jj] = h[q];
    }
  }
}

// ---------------------------------------------------------------------------
// GAT projection (unchanged).
// ---------------------------------------------------------------------------
__global__ __launch_bounds__(256) void gat_feat_kernel(
    const float* __restrict__ feat, const float* __restrict__ gatW,
    const float* __restrict__ a_src, const float* __restrict__ a_dst,
    float* __restrict__ Wh, float* __restrict__ srcv, float* __restrict__ dstv)
{
  __shared__ float sGatW[64 * 128];
  __shared__ float sFeat[8][64];
  __shared__ float sAs[128], sAd[128];
  const int tid = threadIdx.x;
  const int rowbase = blockIdx.x * 8;
  for (int idx = tid; idx < 8192; idx += 256) sGatW[idx] = gatW[idx];
  if (tid < 128) { sAs[tid] = a_src[tid]; sAd[tid] = a_dst[tid]; }
  for (int idx = tid; idx < 512; idx += 256)
    sFeat[idx >> 6][idx & 63] = feat[(size_t)rowbase * 64 + idx];
  __syncthreads();

  const int hf = tid & 127, half = tid >> 7;
  const int h = hf >> 5;
  const float as = sAs[hf], ad = sAd[hf];
  for (int rr = half; rr < 8; rr += 2) {
    float acc = 0.0f;
#pragma unroll 8
    for (int k = 0; k < 64; ++k) acc = fmaf(sFeat[rr][k], sGatW[k * 128 + hf], acc);
    const size_t grow = rowbase + rr;
    Wh[grow * 128 + hf] = acc;
    float ps = acc * as, pd = acc * ad;
#pragma unroll
    for (int m = 16; m >= 1; m >>= 1) {
      ps += __shfl_xor(ps, m, 32);
      pd += __shfl_xor(pd, m, 32);
    }
    if ((hf & 31) == 0) {
      srcv[grow * 4 + h] = ps;
      dstv[grow * 4 + h] = pd;
    }
  }
}

// ---------------------------------------------------------------------------
// Attention + gat aggregation, v3 (single-plane fp16 P/Wh staging).
// Block = (b, 32-row i-tile), 256 thr. Pass-2 thread = (il, jq): 4 CONSECUTIVE
// j -> P packs to fp16x2 LDS writes (kills the per-value hi/lo split that was
// ~320 VALU/thread/tile in v2), attn writes 64B-contiguous/thread. MFMA
// aggregation 4 MF16/tile (was 12 bf16x3). LDS ~41KB -> 3 blocks/CU.
// ---------------------------------------------------------------------------
__global__ __launch_bounds__(256) void attn_kernel(
    const float* __restrict__ Wh, const float* __restrict__ srcp,
    const float* __restrict__ dstp, const int* __restrict__ adj,
    float* __restrict__ attn_out, float* __restrict__ gat_out)
{
  __shared__ __align__(16) float sDst[4096];          // 16 KB
  __shared__ __align__(16) float sSrc[128];
  __shared__ __align__(16) float sIS[128];            // 1/sum (or -1 sentinel)
  __shared__ unsigned int sAdjW[32][32];              // 4 KB bitmask
  __shared__ __align__(16) _Float16 sP[4][32][40];    // [h][i][j] 10 KB
  __shared__ __align__(16) _Float16 sB[4][32][40];    // [h][f][j] 10 KB

  const int tid = threadIdx.x;
  const int bid = blockIdx.x;
  const int swzb = ((bid & 7) << 6) | (bid >> 3);     // XCD-cluster swizzle
  const int b = swzb >> 5;
  const int itile = (swzb & 31) << 5;

  // ---- stage dst, src ----
  for (int idx = tid; idx < 4096; idx += 256) sDst[idx] = dstp[(size_t)b * 4096 + idx];
  if (tid < 128) sSrc[tid] = srcp[((size_t)b * 1024 + itile) * 4 + tid];

  // ---- build adj bitmask ----
  {
    const int row = tid >> 3;
    const int w0 = (tid & 7) << 2;
    const int* arow_g = adj + (size_t)(itile + row) * 1024 + (w0 << 5);
#pragma unroll
    for (int wq = 0; wq < 4; ++wq) {
      unsigned int word = 0;
#pragma unroll
      for (int c4 = 0; c4 < 8; ++c4) {
        int4 v = *reinterpret_cast<const int4*>(arow_g + (wq << 5) + (c4 << 2));
        word |= (unsigned)((v.x != 0) ? 1 : 0) << (c4 * 4 + 0);
        word |= (unsigned)((v.y != 0) ? 1 : 0) << (c4 * 4 + 1);
        word |= (unsigned)((v.z != 0) ? 1 : 0) << (c4 * 4 + 2);
        word |= (unsigned)((v.w != 0) ? 1 : 0) << (c4 * 4 + 3);
      }
      sAdjW[row][w0 + wq] = word;
    }
  }
  __syncthreads();

  // ---- pass 1: row sums (m=0 softmax; logits bounded) ----
  {
    const int i = tid >> 3;
    const int par = tid & 7;
    const float4 sv = *reinterpret_cast<const float4*>(&sSrc[i * 4]);
    f32x4 acc = (f32x4){0.f, 0.f, 0.f, 0.f};
    const unsigned int bit0 = 1u << par;
    for (int kw = 0; kw < 32; ++kw) {
      const unsigned int word = sAdjW[i][kw];
#pragma unroll
      for (int e = 0; e < 4; ++e) {
        const int gj = (kw << 5) + (e << 3) + par;
        const float4 dv = *reinterpret_cast<const float4*>(&sDst[gj * 4]);
        const float mf = (word & (bit0 << (e << 3))) ? 1.0f : 0.0f;
        acc[0] = fmaf(mf, __expf(leaky02(sv.x + dv.x)), acc[0]);
        acc[1] = fmaf(mf, __expf(leaky02(sv.y + dv.y)), acc[1]);
        acc[2] = fmaf(mf, __expf(leaky02(sv.z + dv.z)), acc[2]);
        acc[3] = fmaf(mf, __expf(leaky02(sv.w + dv.w)), acc[3]);
      }
    }
#pragma unroll
    for (int m = 1; m < 8; m <<= 1) {
#pragma unroll
      for (int q = 0; q < 4; ++q) acc[q] += __shfl_xor(acc[q], m, 64);
    }
    if (par == 0) {
      float4 isv;
      isv.x = acc[0] > 0.f ? rcp_fast(acc[0]) : -1.0f;
      isv.y = acc[1] > 0.f ? rcp_fast(acc[1]) : -1.0f;
      isv.z = acc[2] > 0.f ? rcp_fast(acc[2]) : -1.0f;
      isv.w = acc[3] > 0.f ? rcp_fast(acc[3]) : -1.0f;
      *reinterpret_cast<float4*>(&sIS[i * 4]) = isv;
    }
  }
  __syncthreads();

  // ---- pass 2: 32 j-tiles of 32 ----
  const int il = tid >> 3;          // 0..31 (i row)
  const int jq = tid & 7;           // 4-consecutive-j group: j = jq*4..jq*4+3
  const int wv = tid >> 6;          // wave id = head for MFMA phase
  const int l = tid & 63;
  const int jjB = tid & 31;         // B-staging: Wh row within tile
  const int fcB = tid >> 5;         // B-staging: 16-hf chunk

  const float4 sv4 = *reinterpret_cast<const float4*>(&sSrc[il * 4]);
  const float4 is4 = *reinterpret_cast<const float4*>(&sIS[il * 4]);
  f32x4* arow_out = reinterpret_cast<f32x4*>(
      attn_out + ((size_t)(b * 1024 + itile + il)) * 4096);

  f32x4 accg[2][2];
#pragma unroll
  for (int m = 0; m < 2; ++m)
#pragma unroll
    for (int n = 0; n < 2; ++n) accg[m][n] = (f32x4){0.f, 0.f, 0.f, 0.f};

  const int frow = l & 15, fchunk = l >> 4;

  for (int jt = 0; jt < 32; ++jt) {
    const int j0 = jt << 5;
    // -- compute & write phase --
    {
      const unsigned int nib = (sAdjW[il][jt] >> (jq << 2)) & 0xFu;
      float pv[4][4];   // [jl][h]
#pragma unroll
      for (int jl = 0; jl < 4; ++jl) {
        const int gj = j0 + (jq << 2) + jl;
        const float4 dv = *reinterpret_cast<const float4*>(&sDst[gj * 4]);
        const float mf = (nib & (1u << jl)) ? 1.0f : 0.0f;
        f32x4 a4;
        float ex;
        ex = mf * __expf(leaky02(sv4.x + dv.x)); a4[0] = ex * is4.x; if (is4.x < 0.f) a4[0] = 9.765625e-4f;
        ex = mf * __expf(leaky02(sv4.y + dv.y)); a4[1] = ex * is4.y; if (is4.y < 0.f) a4[1] = 9.765625e-4f;
        ex = mf * __expf(leaky02(sv4.z + dv.z)); a4[2] = ex * is4.z; if (is4.z < 0.f) a4[2] = 9.765625e-4f;
        ex = mf * __expf(leaky02(sv4.w + dv.w)); a4[3] = ex * is4.w; if (is4.w < 0.f) a4[3] = 9.765625e-4f;
        __builtin_nontemporal_store(a4, &arow_out[gj]);
        pv[jl][0] = a4[0]; pv[jl][1] = a4[1]; pv[jl][2] = a4[2]; pv[jl][3] = a4[3];
      }
      // P staging: per head, 4 consecutive j -> 2 packed fp16x2 stores
#pragma unroll
      for (int h = 0; h < 4; ++h) {
        fp16x2 lo = __builtin_amdgcn_cvt_pkrtz(pv[0][h], pv[1][h]);
        fp16x2 hi = __builtin_amdgcn_cvt_pkrtz(pv[2][h], pv[3][h]);
        _Float16* dst = &sP[h][il][jq << 2];
        *reinterpret_cast<fp16x2*>(dst)     = lo;
        *reinterpret_cast<fp16x2*>(dst + 2) = hi;
      }
      // B staging: Wh[j0+jjB][fcB*16..+16] -> sB[h][f][jjB], single fp16
      const float* wrow = Wh + ((size_t)(b * 1024 + j0 + jjB)) * 128 + (fcB << 4);
#pragma unroll
      for (int c4 = 0; c4 < 4; ++c4) {
        float4 v = *reinterpret_cast<const float4*>(wrow + (c4 << 2));
        float vv[4] = {v.x, v.y, v.z, v.w};
#pragma unroll
        for (int e = 0; e < 4; ++e) {
          const int hf = (fcB << 4) + (c4 << 2) + e;
          sB[hf >> 5][hf & 31][jjB] = (_Float16)vv[e];
        }
      }
    }
    __syncthreads();
    // -- MFMA phase: wave wv handles head wv (4 MF16) --
    {
      half8 pa[2], wb[2];
#pragma unroll
      for (int m = 0; m < 2; ++m)
        pa[m] = *reinterpret_cast<const half8*>(&sP[wv][m * 16 + frow][fchunk << 3]);
#pragma unroll
      for (int n = 0; n < 2; ++n)
        wb[n] = *reinterpret_cast<const half8*>(&sB[wv][n * 16 + frow][fchunk << 3]);
#pragma unroll
      for (int m = 0; m < 2; ++m)
#pragma unroll
        for (int n = 0; n < 2; ++n)
          accg[m][n] = MF16(pa[m], wb[n], accg[m][n]);
    }
    __syncthreads();
  }

  // ---- epilogue: elu + store gat ----
#pragma unroll
  for (int m = 0; m < 2; ++m)
#pragma unroll
    for (int n = 0; n < 2; ++n)
#pragma unroll
      for (int q = 0; q < 4; ++q) {
        const int i = m * 16 + (l >> 4) * 4 + q;
        const int f = n * 16 + (l & 15);
        float v = accg[m][n][q];
        v = v > 0.0f ? v : (__expf(v) - 1.0f);
        gat_out[((size_t)(b * 1024 + itile + i)) * 128 + wv * 32 + f] = v;
      }
}

// ---------------------------------------------------------------------------
// MLP chain (unchanged).
// ---------------------------------------------------------------------------
__global__ __launch_bounds__(256) void mlp_kernel(
    const float* __restrict__ gat,
    const float* __restrict__ rW1, const float* __restrict__ rb1,
    const float* __restrict__ rW2, const float* __restrict__ rb2,
    const float* __restrict__ fW,  const float* __restrict__ fb,
    const float* __restrict__ ln_g, const float* __restrict__ ln_b,
    const float* __restrict__ nW1, const float* __restrict__ nb1,
    const float* __restrict__ nW2, const float* __restrict__ nb2,
    float* __restrict__ out)
{
  __shared__ float sW[128 * 128];
  __shared__ float sZ[16][128];
  __shared__ float sT[16][128];
  __shared__ float sY[16][32];
  __shared__ float sT2[16][32];
  __shared__ float sB1[128], sB2[128];

  const int tid = threadIdx.x;
  const int rowbase = blockIdx.x * 16;

  for (int idx = tid; idx < 16384; idx += 256) sW[idx] = rW1[idx];
  if (tid < 128) { sB1[tid] = rb1[tid]; sB2[tid] = rb2[tid]; }
  for (int idx = tid; idx < 2048; idx += 256)
    sZ[idx >> 7][idx & 127] = gat[(size_t)rowbase * 128 + idx];
  __syncthreads();

  const int c = tid & 127, rblk = tid >> 7;
  for (int q = 0; q < 8; ++q) {
    const int r = rblk + (q << 1);
    float a = sB1[c];
#pragma unroll 8
    for (int k = 0; k < 128; ++k) a = fmaf(sZ[r][k], sW[k * 128 + c], a);
    sT[r][c] = a > 0.0f ? a : 0.0f;
  }
  __syncthreads();
  for (int idx = tid; idx < 16384; idx += 256) sW[idx] = rW2[idx];
  __syncthreads();
  for (int q = 0; q < 8; ++q) {
    const int r = rblk + (q << 1);
    float a = sB2[c];
#pragma unroll 8
    for (int k = 0; k < 128; ++k) a = fmaf(sT[r][k], sW[k * 128 + c], a);
    a += sZ[r][c];
    sZ[r][c] = a > 0.0f ? a : 0.0f;
  }
  __syncthreads();
  for (int idx = tid; idx < 4096; idx += 256) sW[idx] = fW[idx];
  for (int idx = tid; idx < 1024; idx += 256) {
    sW[4096 + idx] = nW1[idx];
    sW[5120 + idx] = nW2[idx];
  }
  if (tid < 32) {
    sW[6144 + tid] = fb[tid];
    sW[6176 + tid] = ln_g[tid];
    sW[6208 + tid] = ln_b[tid];
    sW[6240 + tid] = nb1[tid];
    sW[6272 + tid] = nb2[tid];
  }
  __syncthreads();

  const int o = tid & 31, rr2 = tid >> 5;
  for (int g = 0; g < 2; ++g) {
    const int r = rr2 + (g << 3);
    float y = sW[6144 + o];
#pragma unroll 8
    for (int k = 0; k < 128; ++k) y = fmaf(sZ[r][k], sW[k * 32 + o], y);
    float mu = y;
#pragma unroll
    for (int m = 16; m >= 1; m >>= 1) mu += __shfl_xor(mu, m, 32);
    mu *= (1.0f / 32.0f);
    const float d = y - mu;
    float var = d * d;
#pragma unroll
    for (int m = 16; m >= 1; m >>= 1) var += __shfl_xor(var, m, 32);
    var *= (1.0f / 32.0f);
    const float yn = d * rsqrtf(var + 1e-5f) * sW[6176 + o] + sW[6208 + o];
    sY[r][o] = tanhf(yn);
  }
  __syncthreads();
  for (int g = 0; g < 2; ++g) {
    const int r = rr2 + (g << 3);
    float a = sW[6240 + o];
#pragma unroll
    for (int k = 0; k < 32; ++k) a = fmaf(sY[r][k], sW[4096 + k * 32 + o], a);
    sT2[r][o] = a > 0.0f ? a : 0.0f;
  }
  __syncthreads();
  for (int g = 0; g < 2; ++g) {
    const int r = rr2 + (g << 3);
    float a = sW[6272 + o];
#pragma unroll
    for (int k = 0; k < 32; ++k) a = fmaf(sT2[r][k], sW[5120 + k * 32 + o], a);
    out[(size_t)(rowbase + r) * 32 + o] = a;
  }
}

// ---------------------------------------------------------------------------
extern "C" void kernel_launch(void* const* d_in, const int* in_sizes, int n_in,
                              void* d_out, int out_size, void* d_ws, size_t ws_size,
                              hipStream_t stream) {
  const float* seq   = (const float*)d_in[0];
  const int*   adj   = (const int*)d_in[1];
  const float* Wih0  = (const float*)d_in[2];
  const float* Whh0  = (const float*)d_in[3];
  const float* bih0  = (const float*)d_in[4];
  const float* bhh0  = (const float*)d_in[5];
  const float* Wih1  = (const float*)d_in[6];
  const float* Whh1  = (const float*)d_in[7];
  const float* bih1  = (const float*)d_in[8];
  const float* bhh1  = (const float*)d_in[9];
  const float* gatW  = (const float*)d_in[10];
  const float* a_src = (const float*)d_in[11];
  const float* a_dst = (const float*)d_in[12];
  const float* rW1   = (const float*)d_in[13];
  const float* rb1   = (const float*)d_in[14];
  const float* rW2   = (const float*)d_in[15];
  const float* rb2   = (const float*)d_in[16];
  const float* fW    = (const float*)d_in[17];
  const float* fb    = (const float*)d_in[18];
  const float* ln_g  = (const float*)d_in[19];
  const float* ln_b  = (const float*)d_in[20];
  const float* nW1   = (const float*)d_in[21];
  const float* nb1   = (const float*)d_in[22];
  const float* nW2   = (const float*)d_in[23];
  const float* nb2   = (const float*)d_in[24];

  float* out  = (float*)d_out;                  // [BN][32] at offset 0
  float* attn = out + (size_t)BN * OO;          // [B,N,N,4] region (268MB)

  float* ws   = (float*)d_ws;
  float* feat = ws;                             // [BN][64]
  float* Wh   = feat + (size_t)BN * 64;         // [BN][128]
  float* srcv = Wh + (size_t)BN * 128;          // [BN][4]
  float* dstv = srcv + (size_t)BN * 4;          // [BN][4]
  float* gat  = dstv + (size_t)BN * 4;          // [BN][128]

  gru_fused_kernel<<<1024, 512, 0, stream>>>(seq, Wih0, Whh0, bih0, bhh0,
                                             Wih1, Whh1, bih1, bhh1, feat);
  gat_feat_kernel<<<2048, 256, 0, stream>>>(feat, gatW, a_src, a_dst, Wh, srcv, dstv);
  attn_kernel<<<512, 256, 0, stream>>>(Wh, srcv, dstv, adj, attn, gat);
  mlp_kernel<<<1024, 256, 0, stream>>>(gat, rW1, rb1, rW2, rb2, fW, fb,
                                       ln_g, ln_b, nW1, nb1, nW2, nb2, out);
}

// Round 14
// 301.740 us; speedup vs baseline: 1.8002x; 1.8002x over previous
//
#include <hip/hip_runtime.h>

// Problem constants
#define BB 16
#define TT 32
#define NN 1024
#define DD 64
#define HH 64
#define BN 16384          // B*N
#define GH 128
#define RR 128
#define OO 32

typedef __attribute__((ext_vector_type(8))) short short8;
typedef __attribute__((ext_vector_type(4))) float f32x4;
typedef __attribute__((ext_vector_type(8))) _Float16 half8;
typedef __attribute__((ext_vector_type(2))) __fp16 fp16x2;

#define MF16(A, B, C) __builtin_amdgcn_mfma_f32_16x16x32_f16((A), (B), (C), 0, 0, 0)

// v_rcp_f32 (~1 ULP): plain 1/x without fast-math is ~10 VALU + ~40cy chain.
__device__ __forceinline__ float rcp_fast(float x) {
  return __builtin_amdgcn_rcpf(x);
}
__device__ __forceinline__ float sigmoid_fast(float x) {
  return rcp_fast(1.0f + __expf(-x));
}
__device__ __forceinline__ float tanh_fast(float x) {
  return fmaf(-2.0f, rcp_fast(__expf(2.0f * x) + 1.0f), 1.0f);
}
__device__ __forceinline__ float leaky02(float x) {
  return fmaxf(x, 0.2f * x);
}

// ---------------------------------------------------------------------------
// Fused 2-layer GRU, v6 (unchanged from R12).
// ---------------------------------------------------------------------------
__global__ __launch_bounds__(512, 4) void gru_fused_kernel(
    const float* __restrict__ x,
    const float* __restrict__ Wih0, const float* __restrict__ Whh0,
    const float* __restrict__ bih0, const float* __restrict__ bhh0,
    const float* __restrict__ Wih1, const float* __restrict__ Whh1,
    const float* __restrict__ bih1, const float* __restrict__ bhh1,
    float* __restrict__ feat)
{
  __shared__ _Float16 sX[2][1024];     // [buf][seq*64 + swz(k)] : 4 KB
  __shared__ _Float16 sH0[2][1024];    // [buf][...] : 4 KB
  __shared__ _Float16 sH1[2][1024];    // [buf][...] : 4 KB

  const int tid = threadIdx.x;
  const int gbase = blockIdx.x * 16;

  const int w = tid >> 6, l = tid & 63;
  const int layer = w >> 2;            // 0 or 1
  const int jt = w & 3;                // 16-col j-group
  const int c = l & 15;                // A row (seq) / D col (j)
  const int rq = l >> 4;               // A k-chunk / D row-group

  const float* Wih = layer ? Wih1 : Wih0;
  const float* Whh = layer ? Whh1 : Whh0;
  const float* bihp = layer ? bih1 : bih0;
  const float* bhhp = layer ? bhh1 : bhh0;

  // ---- weight fragments: global -> reg, fp16 single-plane. [gate][src][ks]
  half8 wf[3][2][2];
#pragma unroll
  for (int g = 0; g < 3; ++g) {
    const int row = g * 64 + jt * 16 + c;
#pragma unroll
    for (int ks = 0; ks < 2; ++ks) {
      const int col = ks * 32 + (rq << 3);
      float4 i0 = *reinterpret_cast<const float4*>(Wih + row * 64 + col);
      float4 i1 = *reinterpret_cast<const float4*>(Wih + row * 64 + col + 4);
      float4 h0 = *reinterpret_cast<const float4*>(Whh + row * 64 + col);
      float4 h1 = *reinterpret_cast<const float4*>(Whh + row * 64 + col + 4);
      float wi[8] = {i0.x, i0.y, i0.z, i0.w, i1.x, i1.y, i1.z, i1.w};
      float wh[8] = {h0.x, h0.y, h0.z, h0.w, h1.x, h1.y, h1.z, h1.w};
      half8 vih, vhh;
#pragma unroll
      for (int e = 0; e < 8; ++e) {
        vih[e] = (_Float16)wi[e];
        vhh[e] = (_Float16)wh[e];
      }
      wf[g][0][ks] = vih;
      wf[g][1][ks] = vhh;
    }
  }

  // ---- X staging role ----
  const int sseq = tid >> 5;           // 0..15
  const int kp = (tid & 31) << 1;      // even k
  const float* xrow = x + (size_t)(gbase + sseq) * (TT * 64) + kp;
  const int sxoff = sseq * 64 + (kp ^ ((sseq & 7) << 3));

  for (int i = tid; i < 1024; i += 512) {
    sH0[0][i] = (_Float16)0.0f;
    sH1[0][i] = (_Float16)0.0f;
  }

  float2 p = *reinterpret_cast<const float2*>(xrow);
  *reinterpret_cast<fp16x2*>(&sX[0][sxoff]) = __builtin_amdgcn_cvt_pkrtz(p.x, p.y);
  p = *reinterpret_cast<const float2*>(xrow + 64);

  const int jj = jt * 16 + c;
  const float br  = bihp[jj]       + bhhp[jj];
  const float bz  = bihp[64 + jj]  + bhhp[64 + jj];
  const float bni = bihp[128 + jj];
  const float bnh = bhhp[128 + jj];

  int ao[2];
#pragma unroll
  for (int ks = 0; ks < 2; ++ks)
    ao[ks] = c * 64 + (((ks << 5) + (rq << 3)) ^ ((c & 7) << 3));
  int hoff[4];
#pragma unroll
  for (int q = 0; q < 4; ++q) {
    const int seq = (rq << 2) + q;
    hoff[q] = seq * 64 + (jj ^ ((seq & 7) << 3));
  }

  float h[4] = {0.0f, 0.0f, 0.0f, 0.0f};

  for (int t = 0; t <= TT; ++t) {
    __syncthreads();
    const int cb = t & 1, nb = cb ^ 1;
    if (t + 1 < TT)
      *reinterpret_cast<fp16x2*>(&sX[nb][sxoff]) = __builtin_amdgcn_cvt_pkrtz(p.x, p.y);
    if (t + 2 < TT)
      p = *reinterpret_cast<const float2*>(xrow + (t + 2) * 64);

    const bool active = layer ? (t >= 1) : (t < TT);
    if (active) {
      const _Float16* xsrc = layer ? &sH0[cb][0] : &sX[cb][0];
      const _Float16* hsrc = layer ? &sH1[nb][0] : &sH0[cb][0];
      _Float16* hdst       = layer ? &sH1[cb][0] : &sH0[nb][0];

      f32x4 accr  = (f32x4){br, br, br, br};
      f32x4 accz  = (f32x4){bz, bz, bz, bz};
      f32x4 accni = (f32x4){bni, bni, bni, bni};
      f32x4 accnh = (f32x4){bnh, bnh, bnh, bnh};

#pragma unroll
      for (int ks = 0; ks < 2; ++ks) {
        const half8 xa = *reinterpret_cast<const half8*>(xsrc + ao[ks]);
        const half8 ha = *reinterpret_cast<const half8*>(hsrc + ao[ks]);
        accr  = MF16(xa, wf[0][0][ks], accr);
        accr  = MF16(ha, wf[0][1][ks], accr);
        accz  = MF16(xa, wf[1][0][ks], accz);
        accz  = MF16(ha, wf[1][1][ks], accz);
        accni = MF16(xa, wf[2][0][ks], accni);
        accnh = MF16(ha, wf[2][1][ks], accnh);
      }

#pragma unroll
      for (int q = 0; q < 4; ++q) {
        float rg = sigmoid_fast(accr[q]);
        float zg = sigmoid_fast(accz[q]);
        float ng = tanh_fast(fmaf(rg, accnh[q], accni[q]));
        float hv = fmaf(zg, h[q] - ng, ng);   // n + z*(h-n)
        h[q] = hv;
        hdst[hoff[q]] = (_Float16)hv;
      }
    }
  }

  if (layer == 1) {
#pragma unroll
    for (int q = 0; q < 4; ++q) {
      const int seq = (rq << 2) + q;
      feat[(size_t)(gbase + seq) * 64 + jj] = h[q];
    }
  }
}

// ---------------------------------------------------------------------------
// GAT projection (unchanged).
// ---------------------------------------------------------------------------
__global__ __launch_bounds__(256) void gat_feat_kernel(
    const float* __restrict__ feat, const float* __restrict__ gatW,
    const float* __restrict__ a_src, const float* __restrict__ a_dst,
    float* __restrict__ Wh, float* __restrict__ srcv, float* __restrict__ dstv)
{
  __shared__ float sGatW[64 * 128];
  __shared__ float sFeat[8][64];
  __shared__ float sAs[128], sAd[128];
  const int tid = threadIdx.x;
  const int rowbase = blockIdx.x * 8;
  for (int idx = tid; idx < 8192; idx += 256) sGatW[idx] = gatW[idx];
  if (tid < 128) { sAs[tid] = a_src[tid]; sAd[tid] = a_dst[tid]; }
  for (int idx = tid; idx < 512; idx += 256)
    sFeat[idx >> 6][idx & 63] = feat[(size_t)rowbase * 64 + idx];
  __syncthreads();

  const int hf = tid & 127, half = tid >> 7;
  const int h = hf >> 5;
  const float as = sAs[hf], ad = sAd[hf];
  for (int rr = half; rr < 8; rr += 2) {
    float acc = 0.0f;
#pragma unroll 8
    for (int k = 0; k < 64; ++k) acc = fmaf(sFeat[rr][k], sGatW[k * 128 + hf], acc);
    const size_t grow = rowbase + rr;
    Wh[grow * 128 + hf] = acc;
    float ps = acc * as, pd = acc * ad;
#pragma unroll
    for (int m = 16; m >= 1; m >>= 1) {
      ps += __shfl_xor(ps, m, 32);
      pd += __shfl_xor(pd, m, 32);
    }
    if ((hf & 31) == 0) {
      srcv[grow * 4 + h] = ps;
      dstv[grow * 4 + h] = pd;
    }
  }
}

// ---------------------------------------------------------------------------
// Attention + gat aggregation, v4 = v2 write mapping + single-plane fp16.
// Block = (b, 32-row i-tile), 256 thr. Pass-2 thread = (il, jsub): j =
// jsub + 8q -> per store instruction 8 lanes fill a contiguous 128B line
// (v3's 4-consecutive-j remap wrote 16B chunks at 64B stride -> 1.94x HBM
// write amplification, 523 MB). P/Wh staged as SINGLE fp16 plane (scalar
// cvt + ds_write_b16; v2's hi/lo split was ~10 VALU/value). 4 MF16/tile.
// sP write banks: (il*20 + q*4 + jsub>>1)%32 covers 32 banks 2-way = free.
// ---------------------------------------------------------------------------
__global__ __launch_bounds__(256) void attn_kernel(
    const float* __restrict__ Wh, const float* __restrict__ srcp,
    const float* __restrict__ dstp, const int* __restrict__ adj,
    float* __restrict__ attn_out, float* __restrict__ gat_out)
{
  __shared__ __align__(16) float sDst[4096];          // 16 KB
  __shared__ __align__(16) float sSrc[128];
  __shared__ __align__(16) float sIS[128];            // 1/sum (or -1 sentinel)
  __shared__ unsigned int sAdjW[32][32];              // 4 KB bitmask
  __shared__ __align__(16) _Float16 sP[4][32][40];    // [h][i][j] 10 KB
  __shared__ __align__(16) _Float16 sB[4][32][40];    // [h][f][j] 10 KB

  const int tid = threadIdx.x;
  const int bid = blockIdx.x;
  const int swzb = ((bid & 7) << 6) | (bid >> 3);     // XCD-cluster swizzle
  const int b = swzb >> 5;
  const int itile = (swzb & 31) << 5;

  // ---- stage dst, src ----
  for (int idx = tid; idx < 4096; idx += 256) sDst[idx] = dstp[(size_t)b * 4096 + idx];
  if (tid < 128) sSrc[tid] = srcp[((size_t)b * 1024 + itile) * 4 + tid];

  // ---- build adj bitmask ----
  {
    const int row = tid >> 3;
    const int w0 = (tid & 7) << 2;
    const int* arow_g = adj + (size_t)(itile + row) * 1024 + (w0 << 5);
#pragma unroll
    for (int wq = 0; wq < 4; ++wq) {
      unsigned int word = 0;
#pragma unroll
      for (int c4 = 0; c4 < 8; ++c4) {
        int4 v = *reinterpret_cast<const int4*>(arow_g + (wq << 5) + (c4 << 2));
        word |= (unsigned)((v.x != 0) ? 1 : 0) << (c4 * 4 + 0);
        word |= (unsigned)((v.y != 0) ? 1 : 0) << (c4 * 4 + 1);
        word |= (unsigned)((v.z != 0) ? 1 : 0) << (c4 * 4 + 2);
        word |= (unsigned)((v.w != 0) ? 1 : 0) << (c4 * 4 + 3);
      }
      sAdjW[row][w0 + wq] = word;
    }
  }
  __syncthreads();

  // ---- pass 1: row sums (m=0 softmax; logits bounded) ----
  {
    const int i = tid >> 3;
    const int par = tid & 7;
    const float4 sv = *reinterpret_cast<const float4*>(&sSrc[i * 4]);
    f32x4 acc = (f32x4){0.f, 0.f, 0.f, 0.f};
    const unsigned int bit0 = 1u << par;
    for (int kw = 0; kw < 32; ++kw) {
      const unsigned int word = sAdjW[i][kw];
#pragma unroll
      for (int e = 0; e < 4; ++e) {
        const int gj = (kw << 5) + (e << 3) + par;
        const float4 dv = *reinterpret_cast<const float4*>(&sDst[gj * 4]);
        const float mf = (word & (bit0 << (e << 3))) ? 1.0f : 0.0f;
        acc[0] = fmaf(mf, __expf(leaky02(sv.x + dv.x)), acc[0]);
        acc[1] = fmaf(mf, __expf(leaky02(sv.y + dv.y)), acc[1]);
        acc[2] = fmaf(mf, __expf(leaky02(sv.z + dv.z)), acc[2]);
        acc[3] = fmaf(mf, __expf(leaky02(sv.w + dv.w)), acc[3]);
      }
    }
#pragma unroll
    for (int m = 1; m < 8; m <<= 1) {
#pragma unroll
      for (int q = 0; q < 4; ++q) acc[q] += __shfl_xor(acc[q], m, 64);
    }
    if (par == 0) {
      float4 isv;
      isv.x = acc[0] > 0.f ? rcp_fast(acc[0]) : -1.0f;
      isv.y = acc[1] > 0.f ? rcp_fast(acc[1]) : -1.0f;
      isv.z = acc[2] > 0.f ? rcp_fast(acc[2]) : -1.0f;
      isv.w = acc[3] > 0.f ? rcp_fast(acc[3]) : -1.0f;
      *reinterpret_cast<float4*>(&sIS[i * 4]) = isv;
    }
  }
  __syncthreads();

  // ---- pass 2: 32 j-tiles of 32 ----
  const int il = tid >> 3;          // 0..31 (i row)
  const int jsub = tid & 7;         // stride-8 j within tile (coalesced)
  const int wv = tid >> 6;          // wave id = head for MFMA phase
  const int l = tid & 63;
  const int jjB = tid & 31;         // B-staging: Wh row within tile
  const int fcB = tid >> 5;         // B-staging: 16-hf chunk

  const float4 sv4 = *reinterpret_cast<const float4*>(&sSrc[il * 4]);
  const float4 is4 = *reinterpret_cast<const float4*>(&sIS[il * 4]);
  f32x4* arow_out = reinterpret_cast<f32x4*>(
      attn_out + ((size_t)(b * 1024 + itile + il)) * 4096);

  f32x4 accg[2][2];
#pragma unroll
  for (int m = 0; m < 2; ++m)
#pragma unroll
    for (int n = 0; n < 2; ++n) accg[m][n] = (f32x4){0.f, 0.f, 0.f, 0.f};

  const int frow = l & 15, fchunk = l >> 4;

  for (int jt = 0; jt < 32; ++jt) {
    const int j0 = jt << 5;
    // -- compute & write phase --
    {
      const unsigned int word = sAdjW[il][jt];
#pragma unroll
      for (int q = 0; q < 4; ++q) {
        const int j = jsub + (q << 3);
        const int gj = j0 + j;
        const float4 dv = *reinterpret_cast<const float4*>(&sDst[gj * 4]);
        const float mf = (word & (1u << j)) ? 1.0f : 0.0f;
        f32x4 a4;
        float ex;
        ex = mf * __expf(leaky02(sv4.x + dv.x)); a4[0] = ex * is4.x; if (is4.x < 0.f) a4[0] = 9.765625e-4f;
        ex = mf * __expf(leaky02(sv4.y + dv.y)); a4[1] = ex * is4.y; if (is4.y < 0.f) a4[1] = 9.765625e-4f;
        ex = mf * __expf(leaky02(sv4.z + dv.z)); a4[2] = ex * is4.z; if (is4.z < 0.f) a4[2] = 9.765625e-4f;
        ex = mf * __expf(leaky02(sv4.w + dv.w)); a4[3] = ex * is4.w; if (is4.w < 0.f) a4[3] = 9.765625e-4f;
        __builtin_nontemporal_store(a4, &arow_out[gj]);
        sP[0][il][j] = (_Float16)a4[0];
        sP[1][il][j] = (_Float16)a4[1];
        sP[2][il][j] = (_Float16)a4[2];
        sP[3][il][j] = (_Float16)a4[3];
      }
      // B staging: Wh[j0+jjB][fcB*16..+16] -> sB[h][f][jjB], single fp16
      const float* wrow = Wh + ((size_t)(b * 1024 + j0 + jjB)) * 128 + (fcB << 4);
#pragma unroll
      for (int c4 = 0; c4 < 4; ++c4) {
        float4 v = *reinterpret_cast<const float4*>(wrow + (c4 << 2));
        float vv[4] = {v.x, v.y, v.z, v.w};
#pragma unroll
        for (int e = 0; e < 4; ++e) {
          const int hf = (fcB << 4) + (c4 << 2) + e;
          sB[hf >> 5][hf & 31][jjB] = (_Float16)vv[e];
        }
      }
    }
    __syncthreads();
    // -- MFMA phase: wave wv handles head wv (4 MF16) --
    {
      half8 pa[2], wb[2];
#pragma unroll
      for (int m = 0; m < 2; ++m)
        pa[m] = *reinterpret_cast<const half8*>(&sP[wv][m * 16 + frow][fchunk << 3]);
#pragma unroll
      for (int n = 0; n < 2; ++n)
        wb[n] = *reinterpret_cast<const half8*>(&sB[wv][n * 16 + frow][fchunk << 3]);
#pragma unroll
      for (int m = 0; m < 2; ++m)
#pragma unroll
        for (int n = 0; n < 2; ++n)
          accg[m][n] = MF16(pa[m], wb[n], accg[m][n]);
    }
    __syncthreads();
  }

  // ---- epilogue: elu + store gat ----
#pragma unroll
  for (int m = 0; m < 2; ++m)
#pragma unroll
    for (int n = 0; n < 2; ++n)
#pragma unroll
      for (int q = 0; q < 4; ++q) {
        const int i = m * 16 + (l >> 4) * 4 + q;
        const int f = n * 16 + (l & 15);
        float v = accg[m][n][q];
        v = v > 0.0f ? v : (__expf(v) - 1.0f);
        gat_out[((size_t)(b * 1024 + itile + i)) * 128 + wv * 32 + f] = v;
      }
}

// ---------------------------------------------------------------------------
// MLP chain (unchanged).
// ---------------------------------------------------------------------------
__global__ __launch_bounds__(256) void mlp_kernel(
    const float* __restrict__ gat,
    const float* __restrict__ rW1, const float* __restrict__ rb1,
    const float* __restrict__ rW2, const float* __restrict__ rb2,
    const float* __restrict__ fW,  const float* __restrict__ fb,
    const float* __restrict__ ln_g, const float* __restrict__ ln_b,
    const float* __restrict__ nW1, const float* __restrict__ nb1,
    const float* __restrict__ nW2, const float* __restrict__ nb2,
    float* __restrict__ out)
{
  __shared__ float sW[128 * 128];
  __shared__ float sZ[16][128];
  __shared__ float sT[16][128];
  __shared__ float sY[16][32];
  __shared__ float sT2[16][32];
  __shared__ float sB1[128], sB2[128];

  const int tid = threadIdx.x;
  const int rowbase = blockIdx.x * 16;

  for (int idx = tid; idx < 16384; idx += 256) sW[idx] = rW1[idx];
  if (tid < 128) { sB1[tid] = rb1[tid]; sB2[tid] = rb2[tid]; }
  for (int idx = tid; idx < 2048; idx += 256)
    sZ[idx >> 7][idx & 127] = gat[(size_t)rowbase * 128 + idx];
  __syncthreads();

  const int c = tid & 127, rblk = tid >> 7;
  for (int q = 0; q < 8; ++q) {
    const int r = rblk + (q << 1);
    float a = sB1[c];
#pragma unroll 8
    for (int k = 0; k < 128; ++k) a = fmaf(sZ[r][k], sW[k * 128 + c], a);
    sT[r][c] = a > 0.0f ? a : 0.0f;
  }
  __syncthreads();
  for (int idx = tid; idx < 16384; idx += 256) sW[idx] = rW2[idx];
  __syncthreads();
  for (int q = 0; q < 8; ++q) {
    const int r = rblk + (q << 1);
    float a = sB2[c];
#pragma unroll 8
    for (int k = 0; k < 128; ++k) a = fmaf(sT[r][k], sW[k * 128 + c], a);
    a += sZ[r][c];
    sZ[r][c] = a > 0.0f ? a : 0.0f;
  }
  __syncthreads();
  for (int idx = tid; idx < 4096; idx += 256) sW[idx] = fW[idx];
  for (int idx = tid; idx < 1024; idx += 256) {
    sW[4096 + idx] = nW1[idx];
    sW[5120 + idx] = nW2[idx];
  }
  if (tid < 32) {
    sW[6144 + tid] = fb[tid];
    sW[6176 + tid] = ln_g[tid];
    sW[6208 + tid] = ln_b[tid];
    sW[6240 + tid] = nb1[tid];
    sW[6272 + tid] = nb2[tid];
  }
  __syncthreads();

  const int o = tid & 31, rr2 = tid >> 5;
  for (int g = 0; g < 2; ++g) {
    const int r = rr2 + (g << 3);
    float y = sW[6144 + o];
#pragma unroll 8
    for (int k = 0; k < 128; ++k) y = fmaf(sZ[r][k], sW[k * 32 + o], y);
    float mu = y;
#pragma unroll
    for (int m = 16; m >= 1; m >>= 1) mu += __shfl_xor(mu, m, 32);
    mu *= (1.0f / 32.0f);
    const float d = y - mu;
    float var = d * d;
#pragma unroll
    for (int m = 16; m >= 1; m >>= 1) var += __shfl_xor(var, m, 32);
    var *= (1.0f / 32.0f);
    const float yn = d * rsqrtf(var + 1e-5f) * sW[6176 + o] + sW[6208 + o];
    sY[r][o] = tanhf(yn);
  }
  __syncthreads();
  for (int g = 0; g < 2; ++g) {
    const int r = rr2 + (g << 3);
    float a = sW[6240 + o];
#pragma unroll
    for (int k = 0; k < 32; ++k) a = fmaf(sY[r][k], sW[4096 + k * 32 + o], a);
    sT2[r][o] = a > 0.0f ? a : 0.0f;
  }
  __syncthreads();
  for (int g = 0; g < 2; ++g) {
    const int r = rr2 + (g << 3);
    float a = sW[6272 + o];
#pragma unroll
    for (int k = 0; k < 32; ++k) a = fmaf(sT2[r][k], sW[5120 + k * 32 + o], a);
    out[(size_t)(rowbase + r) * 32 + o] = a;
  }
}

// ---------------------------------------------------------------------------
extern "C" void kernel_launch(void* const* d_in, const int* in_sizes, int n_in,
                              void* d_out, int out_size, void* d_ws, size_t ws_size,
                              hipStream_t stream) {
  const float* seq   = (const float*)d_in[0];
  const int*   adj   = (const int*)d_in[1];
  const float* Wih0  = (const float*)d_in[2];
  const float* Whh0  = (const float*)d_in[3];
  const float* bih0  = (const float*)d_in[4];
  const float* bhh0  = (const float*)d_in[5];
  const float* Wih1  = (const float*)d_in[6];
  const float* Whh1  = (const float*)d_in[7];
  const float* bih1  = (const float*)d_in[8];
  const float* bhh1  = (const float*)d_in[9];
  const float* gatW  = (const float*)d_in[10];
  const float* a_src = (const float*)d_in[11];
  const float* a_dst = (const float*)d_in[12];
  const float* rW1   = (const float*)d_in[13];
  const float* rb1   = (const float*)d_in[14];
  const float* rW2   = (const float*)d_in[15];
  const float* rb2   = (const float*)d_in[16];
  const float* fW    = (const float*)d_in[17];
  const float* fb    = (const float*)d_in[18];
  const float* ln_g  = (const float*)d_in[19];
  const float* ln_b  = (const float*)d_in[20];
  const float* nW1   = (const float*)d_in[21];
  const float* nb1   = (const float*)d_in[22];
  const float* nW2   = (const float*)d_in[23];
  const float* nb2   = (const float*)d_in[24];

  float* out  = (float*)d_out;                  // [BN][32] at offset 0
  float* attn = out + (size_t)BN * OO;          // [B,N,N,4] region (268MB)

  float* ws   = (float*)d_ws;
  float* feat = ws;                             // [BN][64]
  float* Wh   = feat + (size_t)BN * 64;         // [BN][128]
  float* srcv = Wh + (size_t)BN * 128;          // [BN][4]
  float* dstv = srcv + (size_t)BN * 4;          // [BN][4]
  float* gat  = dstv + (size_t)BN * 4;          // [BN][128]

  gru_fused_kernel<<<1024, 512, 0, stream>>>(seq, Wih0, Whh0, bih0, bhh0,
                                             Wih1, Whh1, bih1, bhh1, feat);
  gat_feat_kernel<<<2048, 256, 0, stream>>>(feat, gatW, a_src, a_dst, Wh, srcv, dstv);
  attn_kernel<<<512, 256, 0, stream>>>(Wh, srcv, dstv, adj, attn, gat);
  mlp_kernel<<<1024, 256, 0, stream>>>(gat, rW1, rb1, rW2, rb2, fW, fb,
                                       ln_g, ln_b, nW1, nb1, nW2, nb2, out);
}

// Round 15
// 298.108 us; speedup vs baseline: 1.8221x; 1.0122x over previous
//
#include <hip/hip_runtime.h>

// Problem constants
#define BB 16
#define TT 32
#define NN 1024
#define DD 64
#define HH 64
#define BN 16384          // B*N
#define GH 128
#define RR 128
#define OO 32

#define LOG2E 1.44269504088896f

typedef __attribute__((ext_vector_type(8))) short short8;
typedef __attribute__((ext_vector_type(4))) float f32x4;
typedef __attribute__((ext_vector_type(8))) _Float16 half8;
typedef __attribute__((ext_vector_type(2))) __fp16 fp16x2;

#define MF16(A, B, C) __builtin_amdgcn_mfma_f32_16x16x32_f16((A), (B), (C), 0, 0, 0)

// v_rcp_f32 (~1 ULP): plain 1/x without fast-math is ~10 VALU + ~40cy chain.
__device__ __forceinline__ float rcp_fast(float x) {
  return __builtin_amdgcn_rcpf(x);
}
__device__ __forceinline__ float exp2_fast(float x) {
  return __builtin_amdgcn_exp2f(x);
}
// Gate funcs taking PRE-SCALED (by log2e) pre-activations: v_exp_f32 is 2^x,
// so folding log2e into weights/biases removes one mul per transcendental.
__device__ __forceinline__ float sigmoid2(float a) {   // a = x*log2e
  return rcp_fast(1.0f + exp2_fast(-a));
}
__device__ __forceinline__ float tanh2(float a) {      // a = x*log2e
  return fmaf(-2.0f, rcp_fast(exp2_fast(2.0f * a) + 1.0f), 1.0f);
}
__device__ __forceinline__ float leaky02(float x) {
  return fmaxf(x, 0.2f * x);
}

// ---------------------------------------------------------------------------
// Fused 2-layer GRU, v7 = v6 + log2e-folded weights (exp2 gates).
// Block = 512 thr = 8 waves, 16 sequences. Wave w: layer = w>>2, jt = w&3.
// Layer-1 skewed 1 step. Weights fp16 single-plane in VGPRs (48 VGPR),
// PRE-SCALED by log2e. Activations single fp16 plane in LDS (12 KB).
// One barrier/step.
// ---------------------------------------------------------------------------
__global__ __launch_bounds__(512, 4) void gru_fused_kernel(
    const float* __restrict__ x,
    const float* __restrict__ Wih0, const float* __restrict__ Whh0,
    const float* __restrict__ bih0, const float* __restrict__ bhh0,
    const float* __restrict__ Wih1, const float* __restrict__ Whh1,
    const float* __restrict__ bih1, const float* __restrict__ bhh1,
    float* __restrict__ feat)
{
  __shared__ _Float16 sX[2][1024];     // [buf][seq*64 + swz(k)] : 4 KB
  __shared__ _Float16 sH0[2][1024];    // [buf][...] : 4 KB
  __shared__ _Float16 sH1[2][1024];    // [buf][...] : 4 KB

  const int tid = threadIdx.x;
  const int gbase = blockIdx.x * 16;

  const int w = tid >> 6, l = tid & 63;
  const int layer = w >> 2;            // 0 or 1
  const int jt = w & 3;                // 16-col j-group
  const int c = l & 15;                // A row (seq) / D col (j)
  const int rq = l >> 4;               // A k-chunk / D row-group

  const float* Wih = layer ? Wih1 : Wih0;
  const float* Whh = layer ? Whh1 : Whh0;
  const float* bihp = layer ? bih1 : bih0;
  const float* bhhp = layer ? bhh1 : bhh0;

  // ---- weight fragments: global -> reg, fp16 single-plane, x log2e ----
  half8 wf[3][2][2];
#pragma unroll
  for (int g = 0; g < 3; ++g) {
    const int row = g * 64 + jt * 16 + c;
#pragma unroll
    for (int ks = 0; ks < 2; ++ks) {
      const int col = ks * 32 + (rq << 3);
      float4 i0 = *reinterpret_cast<const float4*>(Wih + row * 64 + col);
      float4 i1 = *reinterpret_cast<const float4*>(Wih + row * 64 + col + 4);
      float4 h0 = *reinterpret_cast<const float4*>(Whh + row * 64 + col);
      float4 h1 = *reinterpret_cast<const float4*>(Whh + row * 64 + col + 4);
      float wi[8] = {i0.x, i0.y, i0.z, i0.w, i1.x, i1.y, i1.z, i1.w};
      float wh[8] = {h0.x, h0.y, h0.z, h0.w, h1.x, h1.y, h1.z, h1.w};
      half8 vih, vhh;
#pragma unroll
      for (int e = 0; e < 8; ++e) {
        vih[e] = (_Float16)(wi[e] * LOG2E);
        vhh[e] = (_Float16)(wh[e] * LOG2E);
      }
      wf[g][0][ks] = vih;
      wf[g][1][ks] = vhh;
    }
  }

  // ---- X staging role ----
  const int sseq = tid >> 5;           // 0..15
  const int kp = (tid & 31) << 1;      // even k
  const float* xrow = x + (size_t)(gbase + sseq) * (TT * 64) + kp;
  const int sxoff = sseq * 64 + (kp ^ ((sseq & 7) << 3));

  for (int i = tid; i < 1024; i += 512) {
    sH0[0][i] = (_Float16)0.0f;
    sH1[0][i] = (_Float16)0.0f;
  }

  float2 p = *reinterpret_cast<const float2*>(xrow);
  *reinterpret_cast<fp16x2*>(&sX[0][sxoff]) = __builtin_amdgcn_cvt_pkrtz(p.x, p.y);
  p = *reinterpret_cast<const float2*>(xrow + 64);

  // biases for this thread's j column (x log2e)
  const int jj = jt * 16 + c;
  const float br  = (bihp[jj]       + bhhp[jj])      * LOG2E;
  const float bz  = (bihp[64 + jj]  + bhhp[64 + jj]) * LOG2E;
  const float bni = bihp[128 + jj] * LOG2E;
  const float bnh = bhhp[128 + jj] * LOG2E;

  int ao[2];
#pragma unroll
  for (int ks = 0; ks < 2; ++ks)
    ao[ks] = c * 64 + (((ks << 5) + (rq << 3)) ^ ((c & 7) << 3));
  int hoff[4];
#pragma unroll
  for (int q = 0; q < 4; ++q) {
    const int seq = (rq << 2) + q;
    hoff[q] = seq * 64 + (jj ^ ((seq & 7) << 3));
  }

  float h[4] = {0.0f, 0.0f, 0.0f, 0.0f};

  for (int t = 0; t <= TT; ++t) {
    __syncthreads();
    const int cb = t & 1, nb = cb ^ 1;
    if (t + 1 < TT)
      *reinterpret_cast<fp16x2*>(&sX[nb][sxoff]) = __builtin_amdgcn_cvt_pkrtz(p.x, p.y);
    if (t + 2 < TT)
      p = *reinterpret_cast<const float2*>(xrow + (t + 2) * 64);

    const bool active = layer ? (t >= 1) : (t < TT);
    if (active) {
      const _Float16* xsrc = layer ? &sH0[cb][0] : &sX[cb][0];
      const _Float16* hsrc = layer ? &sH1[nb][0] : &sH0[cb][0];
      _Float16* hdst       = layer ? &sH1[cb][0] : &sH0[nb][0];

      f32x4 accr  = (f32x4){br, br, br, br};
      f32x4 accz  = (f32x4){bz, bz, bz, bz};
      f32x4 accni = (f32x4){bni, bni, bni, bni};
      f32x4 accnh = (f32x4){bnh, bnh, bnh, bnh};

#pragma unroll
      for (int ks = 0; ks < 2; ++ks) {
        const half8 xa = *reinterpret_cast<const half8*>(xsrc + ao[ks]);
        const half8 ha = *reinterpret_cast<const half8*>(hsrc + ao[ks]);
        accr  = MF16(xa, wf[0][0][ks], accr);
        accr  = MF16(ha, wf[0][1][ks], accr);
        accz  = MF16(xa, wf[1][0][ks], accz);
        accz  = MF16(ha, wf[1][1][ks], accz);
        accni = MF16(xa, wf[2][0][ks], accni);
        accnh = MF16(ha, wf[2][1][ks], accnh);
      }

#pragma unroll
      for (int q = 0; q < 4; ++q) {
        float rg = sigmoid2(accr[q]);
        float zg = sigmoid2(accz[q]);
        float ng = tanh2(fmaf(rg, accnh[q], accni[q]));
        float hv = fmaf(zg, h[q] - ng, ng);   // n + z*(h-n)
        h[q] = hv;
        hdst[hoff[q]] = (_Float16)hv;
      }
    }
  }

  if (layer == 1) {
#pragma unroll
    for (int q = 0; q < 4; ++q) {
      const int seq = (rq << 2) + q;
      feat[(size_t)(gbase + seq) * 64 + jj] = h[q];
    }
  }
}

// ---------------------------------------------------------------------------
// GAT projection (unchanged).
// ---------------------------------------------------------------------------
__global__ __launch_bounds__(256) void gat_feat_kernel(
    const float* __restrict__ feat, const float* __restrict__ gatW,
    const float* __restrict__ a_src, const float* __restrict__ a_dst,
    float* __restrict__ Wh, float* __restrict__ srcv, float* __restrict__ dstv)
{
  __shared__ float sGatW[64 * 128];
  __shared__ float sFeat[8][64];
  __shared__ float sAs[128], sAd[128];
  const int tid = threadIdx.x;
  const int rowbase = blockIdx.x * 8;
  for (int idx = tid; idx < 8192; idx += 256) sGatW[idx] = gatW[idx];
  if (tid < 128) { sAs[tid] = a_src[tid]; sAd[tid] = a_dst[tid]; }
  for (int idx = tid; idx < 512; idx += 256)
    sFeat[idx >> 6][idx & 63] = feat[(size_t)rowbase * 64 + idx];
  __syncthreads();

  const int hf = tid & 127, half = tid >> 7;
  const int h = hf >> 5;
  const float as = sAs[hf], ad = sAd[hf];
  for (int rr = half; rr < 8; rr += 2) {
    float acc = 0.0f;
#pragma unroll 8
    for (int k = 0; k < 64; ++k) acc = fmaf(sFeat[rr][k], sGatW[k * 128 + hf], acc);
    const size_t grow = rowbase + rr;
    Wh[grow * 128 + hf] = acc;
    float ps = acc * as, pd = acc * ad;
#pragma unroll
    for (int m = 16; m >= 1; m >>= 1) {
      ps += __shfl_xor(ps, m, 32);
      pd += __shfl_xor(pd, m, 32);
    }
    if ((hf & 31) == 0) {
      srcv[grow * 4 + h] = ps;
      dstv[grow * 4 + h] = pd;
    }
  }
}

// ---------------------------------------------------------------------------
// Attention + gat aggregation, v5 = v4 + double-buffered sP/sB (ONE barrier
// per tile; stage of tile t overlaps other waves' MFMA of t-1 -- safe: when
// a wave stages buf[t&1], all waves passed barrier(t-1), which is after
// their mfma(t-2) on that buffer) + exp2 with log2e-prescaled src/dst
// (leaky commutes with positive scale). LDS ~61 KB -> 2 blocks/CU,
// all 512 blocks resident in one round.
// ---------------------------------------------------------------------------
__global__ __launch_bounds__(256) void attn_kernel(
    const float* __restrict__ Wh, const float* __restrict__ srcp,
    const float* __restrict__ dstp, const int* __restrict__ adj,
    float* __restrict__ attn_out, float* __restrict__ gat_out)
{
  __shared__ __align__(16) float sDst[4096];          // 16 KB (x log2e)
  __shared__ __align__(16) float sSrc[128];           // (x log2e)
  __shared__ __align__(16) float sIS[128];            // 1/sum (or -1 sentinel)
  __shared__ unsigned int sAdjW[32][32];              // 4 KB bitmask
  __shared__ __align__(16) _Float16 sP[2][4][32][40]; // [buf][h][i][j] 20 KB
  __shared__ __align__(16) _Float16 sB[2][4][32][40]; // [buf][h][f][j] 20 KB

  const int tid = threadIdx.x;
  const int bid = blockIdx.x;
  const int swzb = ((bid & 7) << 6) | (bid >> 3);     // XCD-cluster swizzle
  const int b = swzb >> 5;
  const int itile = (swzb & 31) << 5;

  // ---- stage dst, src (pre-scaled by log2e so exp(x) -> exp2(x')) ----
  for (int idx = tid; idx < 4096; idx += 256)
    sDst[idx] = dstp[(size_t)b * 4096 + idx] * LOG2E;
  if (tid < 128)
    sSrc[tid] = srcp[((size_t)b * 1024 + itile) * 4 + tid] * LOG2E;

  // ---- build adj bitmask ----
  {
    const int row = tid >> 3;
    const int w0 = (tid & 7) << 2;
    const int* arow_g = adj + (size_t)(itile + row) * 1024 + (w0 << 5);
#pragma unroll
    for (int wq = 0; wq < 4; ++wq) {
      unsigned int word = 0;
#pragma unroll
      for (int c4 = 0; c4 < 8; ++c4) {
        int4 v = *reinterpret_cast<const int4*>(arow_g + (wq << 5) + (c4 << 2));
        word |= (unsigned)((v.x != 0) ? 1 : 0) << (c4 * 4 + 0);
        word |= (unsigned)((v.y != 0) ? 1 : 0) << (c4 * 4 + 1);
        word |= (unsigned)((v.z != 0) ? 1 : 0) << (c4 * 4 + 2);
        word |= (unsigned)((v.w != 0) ? 1 : 0) << (c4 * 4 + 3);
      }
      sAdjW[row][w0 + wq] = word;
    }
  }
  __syncthreads();

  // ---- pass 1: row sums (m=0 softmax; logits bounded) ----
  {
    const int i = tid >> 3;
    const int par = tid & 7;
    const float4 sv = *reinterpret_cast<const float4*>(&sSrc[i * 4]);
    f32x4 acc = (f32x4){0.f, 0.f, 0.f, 0.f};
    const unsigned int bit0 = 1u << par;
    for (int kw = 0; kw < 32; ++kw) {
      const unsigned int word = sAdjW[i][kw];
#pragma unroll
      for (int e = 0; e < 4; ++e) {
        const int gj = (kw << 5) + (e << 3) + par;
        const float4 dv = *reinterpret_cast<const float4*>(&sDst[gj * 4]);
        const float mf = (word & (bit0 << (e << 3))) ? 1.0f : 0.0f;
        acc[0] = fmaf(mf, exp2_fast(leaky02(sv.x + dv.x)), acc[0]);
        acc[1] = fmaf(mf, exp2_fast(leaky02(sv.y + dv.y)), acc[1]);
        acc[2] = fmaf(mf, exp2_fast(leaky02(sv.z + dv.z)), acc[2]);
        acc[3] = fmaf(mf, exp2_fast(leaky02(sv.w + dv.w)), acc[3]);
      }
    }
#pragma unroll
    for (int m = 1; m < 8; m <<= 1) {
#pragma unroll
      for (int q = 0; q < 4; ++q) acc[q] += __shfl_xor(acc[q], m, 64);
    }
    if (par == 0) {
      float4 isv;
      isv.x = acc[0] > 0.f ? rcp_fast(acc[0]) : -1.0f;
      isv.y = acc[1] > 0.f ? rcp_fast(acc[1]) : -1.0f;
      isv.z = acc[2] > 0.f ? rcp_fast(acc[2]) : -1.0f;
      isv.w = acc[3] > 0.f ? rcp_fast(acc[3]) : -1.0f;
      *reinterpret_cast<float4*>(&sIS[i * 4]) = isv;
    }
  }
  __syncthreads();

  // ---- pass 2: 32 j-tiles of 32, single barrier per tile (dbuf) ----
  const int il = tid >> 3;          // 0..31 (i row)
  const int jsub = tid & 7;         // stride-8 j within tile (coalesced)
  const int wv = tid >> 6;          // wave id = head for MFMA phase
  const int l = tid & 63;
  const int jjB = tid & 31;         // B-staging: Wh row within tile
  const int fcB = tid >> 5;         // B-staging: 16-hf chunk

  const float4 sv4 = *reinterpret_cast<const float4*>(&sSrc[il * 4]);
  const float4 is4 = *reinterpret_cast<const float4*>(&sIS[il * 4]);
  f32x4* arow_out = reinterpret_cast<f32x4*>(
      attn_out + ((size_t)(b * 1024 + itile + il)) * 4096);

  f32x4 accg[2][2];
#pragma unroll
  for (int m = 0; m < 2; ++m)
#pragma unroll
    for (int n = 0; n < 2; ++n) accg[m][n] = (f32x4){0.f, 0.f, 0.f, 0.f};

  const int frow = l & 15, fchunk = l >> 4;

  for (int jt = 0; jt < 32; ++jt) {
    const int j0 = jt << 5;
    const int cur = jt & 1;
    // -- stage & write phase (overlaps other waves' MFMA of jt-1) --
    {
      const unsigned int word = sAdjW[il][jt];
#pragma unroll
      for (int q = 0; q < 4; ++q) {
        const int j = jsub + (q << 3);
        const int gj = j0 + j;
        const float4 dv = *reinterpret_cast<const float4*>(&sDst[gj * 4]);
        const float mf = (word & (1u << j)) ? 1.0f : 0.0f;
        f32x4 a4;
        float ex;
        ex = mf * exp2_fast(leaky02(sv4.x + dv.x)); a4[0] = ex * is4.x; if (is4.x < 0.f) a4[0] = 9.765625e-4f;
        ex = mf * exp2_fast(leaky02(sv4.y + dv.y)); a4[1] = ex * is4.y; if (is4.y < 0.f) a4[1] = 9.765625e-4f;
        ex = mf * exp2_fast(leaky02(sv4.z + dv.z)); a4[2] = ex * is4.z; if (is4.z < 0.f) a4[2] = 9.765625e-4f;
        ex = mf * exp2_fast(leaky02(sv4.w + dv.w)); a4[3] = ex * is4.w; if (is4.w < 0.f) a4[3] = 9.765625e-4f;
        __builtin_nontemporal_store(a4, &arow_out[gj]);
        sP[cur][0][il][j] = (_Float16)a4[0];
        sP[cur][1][il][j] = (_Float16)a4[1];
        sP[cur][2][il][j] = (_Float16)a4[2];
        sP[cur][3][il][j] = (_Float16)a4[3];
      }
      // B staging: Wh[j0+jjB][fcB*16..+16] -> sB[cur][h][f][jjB]
      const float* wrow = Wh + ((size_t)(b * 1024 + j0 + jjB)) * 128 + (fcB << 4);
#pragma unroll
      for (int c4 = 0; c4 < 4; ++c4) {
        float4 v = *reinterpret_cast<const float4*>(wrow + (c4 << 2));
        float vv[4] = {v.x, v.y, v.z, v.w};
#pragma unroll
        for (int e = 0; e < 4; ++e) {
          const int hf = (fcB << 4) + (c4 << 2) + e;
          sB[cur][hf >> 5][hf & 31][jjB] = (_Float16)vv[e];
        }
      }
    }
    __syncthreads();
    // -- MFMA phase: wave wv handles head wv (4 MF16) --
    {
      half8 pa[2], wb[2];
#pragma unroll
      for (int m = 0; m < 2; ++m)
        pa[m] = *reinterpret_cast<const half8*>(&sP[cur][wv][m * 16 + frow][fchunk << 3]);
#pragma unroll
      for (int n = 0; n < 2; ++n)
        wb[n] = *reinterpret_cast<const half8*>(&sB[cur][wv][n * 16 + frow][fchunk << 3]);
#pragma unroll
      for (int m = 0; m < 2; ++m)
#pragma unroll
        for (int n = 0; n < 2; ++n)
          accg[m][n] = MF16(pa[m], wb[n], accg[m][n]);
    }
  }

  // ---- epilogue: elu + store gat ----
#pragma unroll
  for (int m = 0; m < 2; ++m)
#pragma unroll
    for (int n = 0; n < 2; ++n)
#pragma unroll
      for (int q = 0; q < 4; ++q) {
        const int i = m * 16 + (l >> 4) * 4 + q;
        const int f = n * 16 + (l & 15);
        float v = accg[m][n][q];
        v = v > 0.0f ? v : (exp2_fast(v * LOG2E) - 1.0f);
        gat_out[((size_t)(b * 1024 + itile + i)) * 128 + wv * 32 + f] = v;
      }
}

// ---------------------------------------------------------------------------
// MLP chain (unchanged).
// ---------------------------------------------------------------------------
__global__ __launch_bounds__(256) void mlp_kernel(
    const float* __restrict__ gat,
    const float* __restrict__ rW1, const float* __restrict__ rb1,
    const float* __restrict__ rW2, const float* __restrict__ rb2,
    const float* __restrict__ fW,  const float* __restrict__ fb,
    const float* __restrict__ ln_g, const float* __restrict__ ln_b,
    const float* __restrict__ nW1, const float* __restrict__ nb1,
    const float* __restrict__ nW2, const float* __restrict__ nb2,
    float* __restrict__ out)
{
  __shared__ float sW[128 * 128];
  __shared__ float sZ[16][128];
  __shared__ float sT[16][128];
  __shared__ float sY[16][32];
  __shared__ float sT2[16][32];
  __shared__ float sB1[128], sB2[128];

  const int tid = threadIdx.x;
  const int rowbase = blockIdx.x * 16;

  for (int idx = tid; idx < 16384; idx += 256) sW[idx] = rW1[idx];
  if (tid < 128) { sB1[tid] = rb1[tid]; sB2[tid] = rb2[tid]; }
  for (int idx = tid; idx < 2048; idx += 256)
    sZ[idx >> 7][idx & 127] = gat[(size_t)rowbase * 128 + idx];
  __syncthreads();

  const int c = tid & 127, rblk = tid >> 7;
  for (int q = 0; q < 8; ++q) {
    const int r = rblk + (q << 1);
    float a = sB1[c];
#pragma unroll 8
    for (int k = 0; k < 128; ++k) a = fmaf(sZ[r][k], sW[k * 128 + c], a);
    sT[r][c] = a > 0.0f ? a : 0.0f;
  }
  __syncthreads();
  for (int idx = tid; idx < 16384; idx += 256) sW[idx] = rW2[idx];
  __syncthreads();
  for (int q = 0; q < 8; ++q) {
    const int r = rblk + (q << 1);
    float a = sB2[c];
#pragma unroll 8
    for (int k = 0; k < 128; ++k) a = fmaf(sT[r][k], sW[k * 128 + c], a);
    a += sZ[r][c];
    sZ[r][c] = a > 0.0f ? a : 0.0f;
  }
  __syncthreads();
  for (int idx = tid; idx < 4096; idx += 256) sW[idx] = fW[idx];
  for (int idx = tid; idx < 1024; idx += 256) {
    sW[4096 + idx] = nW1[idx];
    sW[5120 + idx] = nW2[idx];
  }
  if (tid < 32) {
    sW[6144 + tid] = fb[tid];
    sW[6176 + tid] = ln_g[tid];
    sW[6208 + tid] = ln_b[tid];
    sW[6240 + tid] = nb1[tid];
    sW[6272 + tid] = nb2[tid];
  }
  __syncthreads();

  const int o = tid & 31, rr2 = tid >> 5;
  for (int g = 0; g < 2; ++g) {
    const int r = rr2 + (g << 3);
    float y = sW[6144 + o];
#pragma unroll 8
    for (int k = 0; k < 128; ++k) y = fmaf(sZ[r][k], sW[k * 32 + o], y);
    float mu = y;
#pragma unroll
    for (int m = 16; m >= 1; m >>= 1) mu += __shfl_xor(mu, m, 32);
    mu *= (1.0f / 32.0f);
    const float d = y - mu;
    float var = d * d;
#pragma unroll
    for (int m = 16; m >= 1; m >>= 1) var += __shfl_xor(var, m, 32);
    var *= (1.0f / 32.0f);
    const float yn = d * rsqrtf(var + 1e-5f) * sW[6176 + o] + sW[6208 + o];
    sY[r][o] = tanhf(yn);
  }
  __syncthreads();
  for (int g = 0; g < 2; ++g) {
    const int r = rr2 + (g << 3);
    float a = sW[6240 + o];
#pragma unroll
    for (int k = 0; k < 32; ++k) a = fmaf(sY[r][k], sW[4096 + k * 32 + o], a);
    sT2[r][o] = a > 0.0f ? a : 0.0f;
  }
  __syncthreads();
  for (int g = 0; g < 2; ++g) {
    const int r = rr2 + (g << 3);
    float a = sW[6272 + o];
#pragma unroll
    for (int k = 0; k < 32; ++k) a = fmaf(sT2[r][k], sW[5120 + k * 32 + o], a);
    out[(size_t)(rowbase + r) * 32 + o] = a;
  }
}

// ---------------------------------------------------------------------------
extern "C" void kernel_launch(void* const* d_in, const int* in_sizes, int n_in,
                              void* d_out, int out_size, void* d_ws, size_t ws_size,
                              hipStream_t stream) {
  const float* seq   = (const float*)d_in[0];
  const int*   adj   = (const int*)d_in[1];
  const float* Wih0  = (const float*)d_in[2];
  const float* Whh0  = (const float*)d_in[3];
  const float* bih0  = (const float*)d_in[4];
  const float* bhh0  = (const float*)d_in[5];
  const float* Wih1  = (const float*)d_in[6];
  const float* Whh1  = (const float*)d_in[7];
  const float* bih1  = (const float*)d_in[8];
  const float* bhh1  = (const float*)d_in[9];
  const float* gatW  = (const float*)d_in[10];
  const float* a_src = (const float*)d_in[11];
  const float* a_dst = (const float*)d_in[12];
  const float* rW1   = (const float*)d_in[13];
  const float* rb1   = (const float*)d_in[14];
  const float* rW2   = (const float*)d_in[15];
  const float* rb2   = (const float*)d_in[16];
  const float* fW    = (const float*)d_in[17];
  const float* fb    = (const float*)d_in[18];
  const float* ln_g  = (const float*)d_in[19];
  const float* ln_b  = (const float*)d_in[20];
  const float* nW1   = (const float*)d_in[21];
  const float* nb1   = (const float*)d_in[22];
  const float* nW2   = (const float*)d_in[23];
  const float* nb2   = (const float*)d_in[24];

  float* out  = (float*)d_out;                  // [BN][32] at offset 0
  float* attn = out + (size_t)BN * OO;          // [B,N,N,4] region (268MB)

  float* ws   = (float*)d_ws;
  float* feat = ws;                             // [BN][64]
  float* Wh   = feat + (size_t)BN * 64;         // [BN][128]
  float* srcv = Wh + (size_t)BN * 128;          // [BN][4]
  float* dstv = srcv + (size_t)BN * 4;          // [BN][4]
  float* gat  = dstv + (size_t)BN * 4;          // [BN][128]

  gru_fused_kernel<<<1024, 512, 0, stream>>>(seq, Wih0, Whh0, bih0, bhh0,
                                             Wih1, Whh1, bih1, bhh1, feat);
  gat_feat_kernel<<<2048, 256, 0, stream>>>(feat, gatW, a_src, a_dst, Wh, srcv, dstv);
  attn_kernel<<<512, 256, 0, stream>>>(Wh, srcv, dstv, adj, attn, gat);
  mlp_kernel<<<1024, 256, 0, stream>>>(gat, rW1, rb1, rW2, rb2, fW, fb,
                                       ln_g, ln_b, nW1, nb1, nW2, nb2, out);
}